// Round 4
// baseline (431.323 us; speedup 1.0000x reference)
//
#include <hip/hip_runtime.h>
#include <hip/hip_bf16.h>
#include <math.h>

#define NN 50000
#define EE 800000
#define F_IN 16
#define HID 32
#define HEADS 4
#define HC 128
#define NCLS 5
#define EF 8
#define NEG_SLOPE 0.2f
#define SCAN_BLOCKS 196  // ceil(50000/256)

typedef __attribute__((ext_vector_type(8))) short short8;
typedef __attribute__((ext_vector_type(4))) float floatx4;
typedef __attribute__((ext_vector_type(2))) float floatx2;

__device__ __forceinline__ float lrelu_f(float v) { return v > 0.f ? v : NEG_SLOPE * v; }
__device__ __forceinline__ float elu_f(float v) { return v > 0.f ? v : expm1f(v); }
__device__ __forceinline__ unsigned short f2bf(float v) {
  __hip_bfloat16 b = __float2bfloat16(v);
  unsigned short u; __builtin_memcpy(&u, &b, 2); return u;
}
__device__ __forceinline__ float bf2f(unsigned short u) {
  unsigned v = (unsigned)u << 16; float f; __builtin_memcpy(&f, &v, 4); return f;
}
// fp8 e4m3 HW converts (gfx950). pack: byte0=a, byte1=b. unpack: .x=byte0, .y=byte1
__device__ __forceinline__ unsigned short pk2_fp8(float a, float b) {
  return (unsigned short)__builtin_amdgcn_cvt_pk_fp8_f32(a, b, 0, false);
}
__device__ __forceinline__ unsigned char pk1_fp8(float a) {
  return (unsigned char)__builtin_amdgcn_cvt_pk_fp8_f32(a, a, 0, false);
}
__device__ __forceinline__ floatx2 unpk_fp8(unsigned short u) {
  return __builtin_amdgcn_cvt_pk_f32_fp8((unsigned)u, false);
}

__global__ void __launch_bounds__(256) k_hist(const int* __restrict__ ei, int* __restrict__ counts) {
  int e = blockIdx.x*256 + threadIdx.x;
  if (e >= EE) return;
  atomicAdd(&counts[ei[EE + e]], 1);
}

__global__ void __launch_bounds__(256) k_scan_block(const int* __restrict__ counts, int* __restrict__ bsum) {
  __shared__ int s[256];
  int tid = threadIdx.x;
  int idx = blockIdx.x*256 + tid;
  s[tid] = (idx < NN) ? counts[idx] : 0;
  for (int o = 128; o; o >>= 1) { __syncthreads(); if (tid < o) s[tid] += s[tid + o]; }
  if (tid == 0) bsum[blockIdx.x] = s[0];
}

__global__ void __launch_bounds__(256) k_scan_top(const int* __restrict__ bsum, int* __restrict__ bexcl,
                                                  int* __restrict__ row_start) {
  __shared__ int s[256];
  int tid = threadIdx.x;
  int v = (tid < SCAN_BLOCKS) ? bsum[tid] : 0;
  s[tid] = v; __syncthreads();
  for (int o = 1; o < 256; o <<= 1) {
    int t2 = (tid >= o) ? s[tid - o] : 0;
    __syncthreads();
    s[tid] += t2;
    __syncthreads();
  }
  if (tid < SCAN_BLOCKS) bexcl[tid] = s[tid] - v;
  if (tid == 0) row_start[NN] = EE;
}

__global__ void __launch_bounds__(256) k_scan_final(const int* __restrict__ counts, const int* __restrict__ bexcl,
                                                    int* __restrict__ row_start, int* __restrict__ cursor) {
  __shared__ int s[256];
  int tid = threadIdx.x;
  int idx = blockIdx.x*256 + tid;
  int v = (idx < NN) ? counts[idx] : 0;
  s[tid] = v; __syncthreads();
  for (int o = 1; o < 256; o <<= 1) {
    int t2 = (tid >= o) ? s[tid - o] : 0;
    __syncthreads();
    s[tid] += t2;
    __syncthreads();
  }
  int excl = s[tid] - v + bexcl[blockIdx.x];
  if (idx < NN) { row_start[idx] = excl; cursor[idx] = excl; }
}

// CSR scatter: srcp[pos] = src node; pose[e] = CSR slot of edge e
__global__ void __launch_bounds__(256) k_scatter(const int* __restrict__ ei, int* __restrict__ cursor,
                                                 int* __restrict__ srcp, int* __restrict__ pose) {
  int e = blockIdx.x*256 + threadIdx.x;
  if (e >= EE) return;
  int src = ei[e], dst = ei[EE + e];
  int pos = atomicAdd(&cursor[dst], 1);
  srcp[pos] = src;
  pose[e] = pos;
}

// edge encoder + ve fold; writes a_e for both layers in CSR order as bf16x4 (8 B/edge/layer)
__global__ void __launch_bounds__(256) k_edge_enc(
    const float* __restrict__ eattr, const float* __restrict__ w1, const float* __restrict__ b1,
    const float* __restrict__ w2, const float* __restrict__ b2,
    const float* __restrict__ We1, const float* __restrict__ ae1,
    const float* __restrict__ We2, const float* __restrict__ ae2,
    const int* __restrict__ pose,
    ushort4* __restrict__ ae1c, ushort4* __restrict__ ae2c) {
  __shared__ float sw1[HID*EF], sb1[HID], sw2[HEADS*HID], sb2[HEADS], sve[32];
  int tid = threadIdx.x;
  sw1[tid] = w1[tid];
  if (tid < HID) sb1[tid] = b1[tid];
  if (tid < HEADS*HID) sw2[tid] = w2[tid];
  if (tid < HEADS) sb2[tid] = b2[tid];
  if (tid < 32) {  // ve[layer*16 + k*4 + h] = sum_c We[(h*32+c)*4+k] * ae[h*32+c]
    int layer = tid >> 4, idx = tid & 15, k = idx >> 2, h = idx & 3;
    const float* We = layer ? We2 : We1;
    const float* ae = layer ? ae2 : ae1;
    float s = 0.f;
    for (int c = 0; c < HID; ++c) s += We[(h*HID + c)*HEADS + k] * ae[h*HID + c];
    sve[layer*16 + k*4 + h] = s;
  }
  __syncthreads();
  int e = blockIdx.x*256 + tid;
  if (e >= EE) return;
  int p = pose[e];
  const float4* ap = (const float4*)(eattr + (size_t)e*EF);
  float4 A0 = ap[0], A1 = ap[1];
  float ea0=A0.x, ea1=A0.y, ea2=A0.z, ea3=A0.w, ea4=A1.x, ea5=A1.y, ea6=A1.z, ea7=A1.w;
  float enc0=sb2[0], enc1=sb2[1], enc2=sb2[2], enc3=sb2[3];
  #pragma unroll
  for (int j = 0; j < HID; ++j) {
    float hsum = sb1[j];
    hsum = fmaf(ea0, sw1[j*EF+0], hsum); hsum = fmaf(ea1, sw1[j*EF+1], hsum);
    hsum = fmaf(ea2, sw1[j*EF+2], hsum); hsum = fmaf(ea3, sw1[j*EF+3], hsum);
    hsum = fmaf(ea4, sw1[j*EF+4], hsum); hsum = fmaf(ea5, sw1[j*EF+5], hsum);
    hsum = fmaf(ea6, sw1[j*EF+6], hsum); hsum = fmaf(ea7, sw1[j*EF+7], hsum);
    hsum = fmaxf(hsum, 0.f);
    enc0 = fmaf(hsum, sw2[0*HID+j], enc0);
    enc1 = fmaf(hsum, sw2[1*HID+j], enc1);
    enc2 = fmaf(hsum, sw2[2*HID+j], enc2);
    enc3 = fmaf(hsum, sw2[3*HID+j], enc3);
  }
  ushort4 r1, r2;
  r1.x = f2bf(enc0*sve[0]  + enc1*sve[4]  + enc2*sve[8]   + enc3*sve[12]);
  r1.y = f2bf(enc0*sve[1]  + enc1*sve[5]  + enc2*sve[9]   + enc3*sve[13]);
  r1.z = f2bf(enc0*sve[2]  + enc1*sve[6]  + enc2*sve[10]  + enc3*sve[14]);
  r1.w = f2bf(enc0*sve[3]  + enc1*sve[7]  + enc2*sve[11]  + enc3*sve[15]);
  r2.x = f2bf(enc0*sve[16] + enc1*sve[20] + enc2*sve[24]  + enc3*sve[28]);
  r2.y = f2bf(enc0*sve[17] + enc1*sve[21] + enc2*sve[25]  + enc3*sve[29]);
  r2.z = f2bf(enc0*sve[18] + enc1*sve[22] + enc2*sve[26]  + enc3*sve[30]);
  r2.w = f2bf(enc0*sve[19] + enc1*sve[23] + enc2*sve[27]  + enc3*sve[31]);
  ae1c[p] = r1; ae2c[p] = r2;
}

// layer-1 node phase: xp8 = fp8(x @ W^T), a_src/a_dst per (node,head)
__global__ void __launch_bounds__(128) k_node1(const float* __restrict__ x, const float* __restrict__ W,
                                               const float* __restrict__ as_, const float* __restrict__ ad_,
                                               unsigned short* __restrict__ xp8u, float* __restrict__ a_src,
                                               float* __restrict__ a_dst) {
  __shared__ float sW[HC*17];
  __shared__ float sas[HC], sad[HC];
  __shared__ float sx[F_IN];
  int tid = threadIdx.x;
  for (int i = tid; i < HC*F_IN; i += 128) { int r = i >> 4, k = i & 15; sW[r*17 + k] = W[i]; }
  sas[tid] = as_[tid]; sad[tid] = ad_[tid];
  int h = tid >> 5;
  for (int n = blockIdx.x; n < NN; n += gridDim.x) {
    __syncthreads();
    if (tid < F_IN) sx[tid] = x[(size_t)n*F_IN + tid];
    __syncthreads();
    float xv = 0.f;
    #pragma unroll
    for (int k = 0; k < F_IN; ++k) xv = fmaf(sx[k], sW[tid*17 + k], xv);
    float xo = __shfl_xor(xv, 1);
    if (!(tid & 1)) xp8u[(size_t)n*64 + (tid >> 1)] = pk2_fp8(xv, xo);
    float vs = xv * sas[tid], vd = xv * sad[tid];
    #pragma unroll
    for (int m = 16; m; m >>= 1) { vs += __shfl_xor(vs, m); vd += __shfl_xor(vd, m); }
    if ((tid & 31) == 0) { a_src[n*HEADS + h] = vs; a_dst[n*HEADS + h] = vd; }
  }
}

// wave-per-node layer-1: inline scores (exp(lrelu)) + aggregate + softmax-norm + bias + elu -> h1 bf16
__global__ void __launch_bounds__(256) k_agg1(const int* __restrict__ row_start, const int* __restrict__ srcp,
                                              const unsigned short* __restrict__ xp8u,
                                              const unsigned short* __restrict__ ae1c,
                                              const float* __restrict__ a_src, const float* __restrict__ a_dst,
                                              const float* __restrict__ bias, unsigned short* __restrict__ h1b) {
  int wv = threadIdx.x >> 6, lane = threadIdx.x & 63;
  int n = blockIdx.x*4 + wv;
  if (n >= NN) return;
  int h = lane >> 4, c2 = lane*2;
  int beg = row_start[n], end = row_start[n+1];
  float adh = a_dst[n*HEADS + h];
  float acc0 = 0.f, acc1 = 0.f, ssum = 0.f;
  for (int cb = beg; cb < end; cb += 64) {
    int navail = end - cb;
    int cnt = navail < 64 ? navail : 64;
    int sv = srcp[cb + (lane < navail ? lane : navail - 1)];
    int j = 0;
    for (; j + 3 < cnt; j += 4) {
      int s0 = __builtin_amdgcn_readlane(sv, j);
      int s1 = __builtin_amdgcn_readlane(sv, j+1);
      int s2 = __builtin_amdgcn_readlane(sv, j+2);
      int s3 = __builtin_amdgcn_readlane(sv, j+3);
      unsigned short g0 = xp8u[(size_t)s0*64 + lane];
      unsigned short g1 = xp8u[(size_t)s1*64 + lane];
      unsigned short g2 = xp8u[(size_t)s2*64 + lane];
      unsigned short g3 = xp8u[(size_t)s3*64 + lane];
      float as0 = a_src[s0*HEADS + h], as1 = a_src[s1*HEADS + h];
      float as2 = a_src[s2*HEADS + h], as3 = a_src[s3*HEADS + h];
      float ae0 = bf2f(ae1c[(size_t)(cb+j)*4 + h]),   ae1_ = bf2f(ae1c[(size_t)(cb+j+1)*4 + h]);
      float ae2_ = bf2f(ae1c[(size_t)(cb+j+2)*4 + h]), ae3_ = bf2f(ae1c[(size_t)(cb+j+3)*4 + h]);
      float w0 = __expf(lrelu_f(as0 + adh + ae0));
      float w1 = __expf(lrelu_f(as1 + adh + ae1_));
      float w2 = __expf(lrelu_f(as2 + adh + ae2_));
      float w3 = __expf(lrelu_f(as3 + adh + ae3_));
      floatx2 x0 = unpk_fp8(g0), x1 = unpk_fp8(g1), x2 = unpk_fp8(g2), x3 = unpk_fp8(g3);
      ssum += (w0 + w1) + (w2 + w3);
      acc0 = fmaf(w0, x0.x, fmaf(w1, x1.x, fmaf(w2, x2.x, fmaf(w3, x3.x, acc0))));
      acc1 = fmaf(w0, x0.y, fmaf(w1, x1.y, fmaf(w2, x2.y, fmaf(w3, x3.y, acc1))));
    }
    for (; j < cnt; ++j) {
      int s0 = __builtin_amdgcn_readlane(sv, j);
      unsigned short g0 = xp8u[(size_t)s0*64 + lane];
      float as0 = a_src[s0*HEADS + h];
      float ae0 = bf2f(ae1c[(size_t)(cb+j)*4 + h]);
      float w0 = __expf(lrelu_f(as0 + adh + ae0));
      floatx2 x0 = unpk_fp8(g0);
      ssum += w0;
      acc0 = fmaf(w0, x0.x, acc0); acc1 = fmaf(w0, x0.y, acc1);
    }
  }
  float inv = 1.f / (ssum + 1e-16f);
  ushort2 o;
  o.x = f2bf(elu_f(acc0*inv + bias[c2]));
  o.y = f2bf(elu_f(acc1*inv + bias[c2+1]));
  ((ushort2*)h1b)[(size_t)n*64 + lane] = o;
}

__global__ void __launch_bounds__(256) k_tobf16(const float* __restrict__ in, unsigned short* __restrict__ out, int n) {
  int i = blockIdx.x*256 + threadIdx.x;
  if (i < n) out[i] = f2bf(in[i]);
}

// layer-2 node GEMM via 16x16x32 bf16 MFMA; epilogue: write xp2 fp8 + a_src/a_dst coefs from f32 acc
__global__ void __launch_bounds__(256) k_xp2(const unsigned short* __restrict__ h1b,
                                             const unsigned short* __restrict__ w2b,
                                             const float* __restrict__ as_, const float* __restrict__ ad_,
                                             unsigned char* __restrict__ xp8, float* __restrict__ a_src,
                                             float* __restrict__ a_dst) {
  int wave = threadIdx.x >> 6;
  int lane = threadIdx.x & 63;
  int m0 = (blockIdx.x*4 + wave)*16;
  if (m0 >= NN) return;
  int ln = lane & 15;
  int quad = lane >> 4;
  const short8* arow = (const short8*)(h1b + (size_t)(m0 + ln)*HC) + quad;
  short8 a[4];
  #pragma unroll
  for (int kc = 0; kc < 4; ++kc) a[kc] = arow[kc*4];
  float sp[4] = {0.f,0.f,0.f,0.f}, dp[4] = {0.f,0.f,0.f,0.f};
  #pragma unroll
  for (int n0 = 0; n0 < 8; ++n0) {
    int head = n0 >> 1, sub = n0 & 1;
    const short8* brow = (const short8*)(w2b + (size_t)(n0*16 + ln)*HC) + quad;
    floatx4 acc = {0.f, 0.f, 0.f, 0.f};
    #pragma unroll
    for (int kc = 0; kc < 4; ++kc) {
      short8 b = brow[kc*4];
      acc = __builtin_amdgcn_mfma_f32_16x16x32_bf16(a[kc], b, acc, 0, 0, 0);
    }
    float a_sv = as_[head*HID + sub*16 + ln];
    float a_dv = ad_[head*HID + sub*16 + ln];
    #pragma unroll
    for (int r = 0; r < 4; ++r) {
      float v = acc[r];
      xp8[(size_t)(m0 + quad*4 + r)*HC + n0*16 + ln] = pk1_fp8(v);
      sp[r] = fmaf(v, a_sv, sp[r]);
      dp[r] = fmaf(v, a_dv, dp[r]);
    }
    if (sub) {
      #pragma unroll
      for (int r = 0; r < 4; ++r) {
        #pragma unroll
        for (int m = 1; m < 16; m <<= 1) {
          sp[r] += __shfl_xor(sp[r], m);
          dp[r] += __shfl_xor(dp[r], m);
        }
      }
      if (ln == 0) {
        #pragma unroll
        for (int r = 0; r < 4; ++r) {
          a_src[(size_t)(m0 + quad*4 + r)*HEADS + head] = sp[r];
          a_dst[(size_t)(m0 + quad*4 + r)*HEADS + head] = dp[r];
        }
      }
      #pragma unroll
      for (int r = 0; r < 4; ++r) { sp[r] = 0.f; dp[r] = 0.f; }
    }
  }
}

// wave-per-node layer-2: inline scores + aggregate + elu + skip + classifier
__global__ void __launch_bounds__(256) k_final(const int* __restrict__ row_start, const int* __restrict__ srcp,
                                               const unsigned short* __restrict__ xp8u,
                                               const unsigned short* __restrict__ ae2c,
                                               const float* __restrict__ a_src, const float* __restrict__ a_dst,
                                               const float* __restrict__ g2b, const float* __restrict__ x,
                                               const float* __restrict__ skw, const float* __restrict__ skb,
                                               const float* __restrict__ clw, const float* __restrict__ clb,
                                               float* __restrict__ out) {
  int wv = threadIdx.x >> 6, lane = threadIdx.x & 63;
  int n = blockIdx.x*4 + wv;
  if (n >= NN) return;
  int h = lane >> 4, c2 = lane*2;
  int beg = row_start[n], end = row_start[n+1];
  float adh = a_dst[n*HEADS + h];
  float acc0 = 0.f, acc1 = 0.f, ssum = 0.f;
  for (int cb = beg; cb < end; cb += 64) {
    int navail = end - cb;
    int cnt = navail < 64 ? navail : 64;
    int sv = srcp[cb + (lane < navail ? lane : navail - 1)];
    int j = 0;
    for (; j + 3 < cnt; j += 4) {
      int s0 = __builtin_amdgcn_readlane(sv, j);
      int s1 = __builtin_amdgcn_readlane(sv, j+1);
      int s2 = __builtin_amdgcn_readlane(sv, j+2);
      int s3 = __builtin_amdgcn_readlane(sv, j+3);
      unsigned short g0 = xp8u[(size_t)s0*64 + lane];
      unsigned short g1 = xp8u[(size_t)s1*64 + lane];
      unsigned short g2 = xp8u[(size_t)s2*64 + lane];
      unsigned short g3 = xp8u[(size_t)s3*64 + lane];
      float as0 = a_src[s0*HEADS + h], as1 = a_src[s1*HEADS + h];
      float as2 = a_src[s2*HEADS + h], as3 = a_src[s3*HEADS + h];
      float ae0 = bf2f(ae2c[(size_t)(cb+j)*4 + h]),   ae1_ = bf2f(ae2c[(size_t)(cb+j+1)*4 + h]);
      float ae2_ = bf2f(ae2c[(size_t)(cb+j+2)*4 + h]), ae3_ = bf2f(ae2c[(size_t)(cb+j+3)*4 + h]);
      float w0 = __expf(lrelu_f(as0 + adh + ae0));
      float w1 = __expf(lrelu_f(as1 + adh + ae1_));
      float w2 = __expf(lrelu_f(as2 + adh + ae2_));
      float w3 = __expf(lrelu_f(as3 + adh + ae3_));
      floatx2 x0 = unpk_fp8(g0), x1 = unpk_fp8(g1), x2 = unpk_fp8(g2), x3 = unpk_fp8(g3);
      ssum += (w0 + w1) + (w2 + w3);
      acc0 = fmaf(w0, x0.x, fmaf(w1, x1.x, fmaf(w2, x2.x, fmaf(w3, x3.x, acc0))));
      acc1 = fmaf(w0, x0.y, fmaf(w1, x1.y, fmaf(w2, x2.y, fmaf(w3, x3.y, acc1))));
    }
    for (; j < cnt; ++j) {
      int s0 = __builtin_amdgcn_readlane(sv, j);
      unsigned short g0 = xp8u[(size_t)s0*64 + lane];
      float as0 = a_src[s0*HEADS + h];
      float ae0 = bf2f(ae2c[(size_t)(cb+j)*4 + h]);
      float w0 = __expf(lrelu_f(as0 + adh + ae0));
      floatx2 x0 = unpk_fp8(g0);
      ssum += w0;
      acc0 = fmaf(w0, x0.x, acc0); acc1 = fmaf(w0, x0.y, acc1);
    }
  }
  float inv = 1.f / (ssum + 1e-16f);
  float v0 = elu_f(acc0*inv + g2b[c2]);
  float v1 = elu_f(acc1*inv + g2b[c2+1]);
  float xv = x[(size_t)n*F_IN + (lane & 15)];
  float sk0 = skb[c2], sk1 = skb[c2+1];
  #pragma unroll
  for (int k = 0; k < F_IN; ++k) {
    float xk = __shfl(xv, k);
    sk0 = fmaf(xk, skw[c2*F_IN + k], sk0);
    sk1 = fmaf(xk, skw[(c2+1)*F_IN + k], sk1);
  }
  float r0 = v0 + sk0, r1 = v1 + sk1;
  #pragma unroll
  for (int k = 0; k < NCLS; ++k) {
    float p = fmaf(r0, clw[k*HC + c2], r1*clw[k*HC + c2 + 1]);
    #pragma unroll
    for (int m = 32; m; m >>= 1) p += __shfl_xor(p, m);
    if (lane == 0) out[(size_t)n*NCLS + k] = p + clb[k];
  }
}

extern "C" void kernel_launch(void* const* d_in, const int* in_sizes, int n_in,
                              void* d_out, int out_size, void* d_ws, size_t ws_size,
                              hipStream_t stream) {
  const float* x      = (const float*)d_in[0];
  const int*   ei     = (const int*)d_in[1];
  const float* eattr  = (const float*)d_in[2];
  const float* ee_w1  = (const float*)d_in[3];
  const float* ee_b1  = (const float*)d_in[4];
  const float* ee_w2  = (const float*)d_in[5];
  const float* ee_b2  = (const float*)d_in[6];
  const float* g1_W   = (const float*)d_in[7];
  const float* g1_We  = (const float*)d_in[8];
  const float* g1_as  = (const float*)d_in[9];
  const float* g1_ad  = (const float*)d_in[10];
  const float* g1_ae  = (const float*)d_in[11];
  const float* g1_b   = (const float*)d_in[12];
  const float* g2_W   = (const float*)d_in[13];
  const float* g2_We  = (const float*)d_in[14];
  const float* g2_as  = (const float*)d_in[15];
  const float* g2_ad  = (const float*)d_in[16];
  const float* g2_ae  = (const float*)d_in[17];
  const float* g2_b   = (const float*)d_in[18];
  const float* skip_w = (const float*)d_in[19];
  const float* skip_b = (const float*)d_in[20];
  const float* cls_w  = (const float*)d_in[21];
  const float* cls_b  = (const float*)d_in[22];
  float* out = (float*)d_out;
  (void)in_sizes; (void)n_in; (void)out_size; (void)ws_size;

  char* ws = (char*)d_ws;
  size_t off = 0;
  auto alloc = [&](size_t bytes) -> void* {
    void* p = ws + off;
    off = (off + bytes + 255) & ~(size_t)255;
    return p;
  };
  int* counts          = (int*)alloc((size_t)NN*4);
  int* row_start       = (int*)alloc((size_t)(NN + 1)*4);
  int* cursor          = (int*)alloc((size_t)NN*4);
  int* bexcl           = (int*)alloc(256*4);
  int* bsum            = (int*)alloc(256*4);
  int* srcp            = (int*)alloc((size_t)EE*4);
  int* pose            = (int*)alloc((size_t)EE*4);
  ushort4* ae1c        = (ushort4*)alloc((size_t)EE*8);
  ushort4* ae2c        = (ushort4*)alloc((size_t)EE*8);
  unsigned short* xp8u = (unsigned short*)alloc((size_t)NN*64*2);  // fp8 rows (128 B), both layers
  unsigned short* h1b  = (unsigned short*)alloc((size_t)NN*HC*2);
  unsigned short* w2b  = (unsigned short*)alloc((size_t)HC*HC*2);
  float* a_src         = (float*)alloc((size_t)NN*HEADS*4);  // reused layer-2
  float* a_dst         = (float*)alloc((size_t)NN*HEADS*4);

  hipMemsetAsync(counts, 0, (size_t)NN*4, stream);
  k_hist<<<EE/256, 256, 0, stream>>>(ei, counts);
  k_scan_block<<<SCAN_BLOCKS, 256, 0, stream>>>(counts, bsum);
  k_scan_top<<<1, 256, 0, stream>>>(bsum, bexcl, row_start);
  k_scan_final<<<SCAN_BLOCKS, 256, 0, stream>>>(counts, bexcl, row_start, cursor);
  k_scatter<<<EE/256, 256, 0, stream>>>(ei, cursor, srcp, pose);
  k_edge_enc<<<EE/256, 256, 0, stream>>>(eattr, ee_w1, ee_b1, ee_w2, ee_b2,
                                         g1_We, g1_ae, g2_We, g2_ae, pose, ae1c, ae2c);
  k_node1<<<2048, 128, 0, stream>>>(x, g1_W, g1_as, g1_ad, xp8u, a_src, a_dst);
  k_agg1<<<(NN + 3)/4, 256, 0, stream>>>(row_start, srcp, xp8u, (const unsigned short*)ae1c,
                                         a_src, a_dst, g1_b, h1b);
  k_tobf16<<<(HC*HC)/256, 256, 0, stream>>>(g2_W, w2b, HC*HC);
  k_xp2<<<(NN/16 + 3)/4, 256, 0, stream>>>(h1b, w2b, g2_as, g2_ad,
                                           (unsigned char*)xp8u, a_src, a_dst);
  k_final<<<(NN + 3)/4, 256, 0, stream>>>(row_start, srcp, xp8u, (const unsigned short*)ae2c,
                                          a_src, a_dst, g2_b, x, skip_w, skip_b, cls_w, cls_b, out);
}